// Round 21
// baseline (108.132 us; speedup 1.0000x reference)
//
#include <hip/hip_runtime.h>

#define HH 1024
#define WW 1024
#define TW 116         // output cols per tile (even -> float2-aligned halo)
#define WLP 144        // colsum slots per row (max touched 135, no clamps)
#define NSLOT 1024     // partial-sum slots (atomic contention spread)
#define SSIM_C1 1e-4f
#define SSIM_C2 9e-4f

typedef float vf2 __attribute__((ext_vector_type(2)));
typedef __fp16 h2 __attribute__((ext_vector_type(2)));
typedef __fp16 h4 __attribute__((ext_vector_type(4)));

__global__ void ssim_ws_init(float* ws) { ws[threadIdx.x] = 0.f; }

// One wave per block: fully autonomous 8-output-row task. Decorrelates wave
// phases (waves retire/launch individually -> natural pipeline stagger across
// resident waves), finer tail. s_setprio(1) in compute favors compute-phase
// waves over load-bursting ones (T5; applicable to independent 1-wave blocks).
__global__ __launch_bounds__(64, 8) void ssim_main(const float* __restrict__ img1,
                                                   const float* __restrict__ img2,
                                                   const float* __restrict__ window,
                                                   float* __restrict__ ws)
{
    __shared__ h4 cs4[8][WLP];       // 9.2 KB per 1-wave block

    const int tx = blockIdx.x;       // col tile: 0..8
    const int by = blockIdx.y;       // 8-row band: 0..127
    const int b  = blockIdx.z;       // batch
    const int cg = threadIdx.x;      // lane 0..63 = column pair
    const int C0 = tx * TW;
    const int R0 = by * 8;
    const size_t ibase = (size_t)b * (size_t)(HH * WW);
    const float w = window[0];

    // ---- Phase 1: load 18 rows (x2 images), vertical 11-sums, emit 8 rows ----
    {
        const int gc = C0 - 6 + 2 * cg;  // even -> 8B-aligned float2
        const int jb = __builtin_amdgcn_readfirstlane(R0 - 5);

        vf2 X[18], Y[18];
        const bool rin = (R0 >= 8) && (R0 <= HH - 16);   // jb>=0 && jb+17<HH
        const bool cin = (tx >= 1) && (tx <= 7);
        if (rin && cin) {
            const vf2* p1 = (const vf2*)(img1 + ibase + gc);
            const vf2* p2 = (const vf2*)(img2 + ibase + gc);
#pragma unroll
            for (int k = 0; k < 18; ++k) {
                const size_t off = (size_t)(jb + k) * (WW / 2);
                X[k] = p1[off];
                Y[k] = p2[off];
            }
        } else {
            const bool cok = (unsigned)gc < (unsigned)WW;
            const int gcc = min(max(gc, 0), WW - 2);
            const vf2* p1 = (const vf2*)(img1 + ibase + gcc);
            const vf2* p2 = (const vf2*)(img2 + ibase + gcc);
#pragma unroll
            for (int k = 0; k < 18; ++k) {
                const int j  = jb + k;
                const int jc = min(max(j, 0), HH - 1);
                const size_t off = (size_t)jc * (WW / 2);
                vf2 x = p1[off], y = p2[off];
                const bool ok = cok && ((unsigned)j < (unsigned)HH);
                if (!ok) { x = (vf2){0.f, 0.f}; y = (vf2){0.f, 0.f}; }
                X[k] = x; Y[k] = y;
            }
        }
        __builtin_amdgcn_sched_barrier(0);   // keep the 36-load burst batched
        __builtin_amdgcn_s_setprio(1);       // entering compute: favor this wave

        vf2 s1 = {0.f, 0.f}, s2 = {0.f, 0.f}, sp = {0.f, 0.f}, sq = {0.f, 0.f};
#pragma unroll
        for (int k = 0; k < 11; ++k) {
            const vf2 x = X[k], y = Y[k];
            const vf2 aa = x + y, dd = x - y;
            s1 += x; s2 += y;
            sp += aa * aa;
            sq += dd * dd;
        }
#pragma unroll
        for (int i = 0; i < 8; ++i) {
            if (i > 0) {
                const vf2 xn = X[10 + i], yn = Y[10 + i];   // static idx
                const vf2 xo = X[i - 1],  yo = Y[i - 1];
                const vf2 an = xn + yn, dn = xn - yn;
                const vf2 ao = xo + yo, dq = xo - yo;
                s1 += xn - xo;
                s2 += yn - yo;
                sp += (an - ao) * (an + ao);
                sq += (dn - dq) * (dn + dq);
            }
            const h2 loa = __builtin_amdgcn_cvt_pkrtz(s1.x, s2.x);
            const h2 hia = __builtin_amdgcn_cvt_pkrtz(sp.x, sq.x);
            const h2 lob = __builtin_amdgcn_cvt_pkrtz(s1.y, s2.y);
            const h2 hib = __builtin_amdgcn_cvt_pkrtz(sp.y, sq.y);
            cs4[i][(2 * cg)     ^ i] = __builtin_shufflevector(loa, hia, 0, 1, 2, 3);
            cs4[i][(2 * cg + 1) ^ i] = __builtin_shufflevector(lob, hib, 0, 1, 2, 3);
        }
    }
    // No __syncthreads: single wave; compiler orders LDS write->read via lgkmcnt.

    // ---- Phase 2: lane = row(cg&7) x seg(cg>>3); near-uniform segs
    // (4x15 + 4x14 cols) -> <=1 masked iteration per lane. Two 8-col slides
    // with win CARRIED across; peak live set v[19] (R15/R18 spill lesson).
    // Raw-sum space: sigs = 0.5u(P+Q)-m11-m22, s12 = 0.25u(P-Q)-m12,
    // C1' = C1*u^2, C2' = C2*u^2 (u = 1/w).
    float ssum = 0.f;
    {
        const float u   = __builtin_amdgcn_rcpf(w);   // = 121
        const float hu  = 0.5f  * u;
        const float qu  = 0.25f * u;
        const float C1p = SSIM_C1 * u * u;
        const float C2p = SSIM_C2 * u * u;
        const int r    = cg & 7;
        const int seg  = cg >> 3;                  // 8 segments
        const int c0   = seg * 15 - max(0, seg - 4);   // 0,15,30,45,60,74,88,102
        const int full = 15 - (seg >= 4);              // 15 or 14
        const int TWa  = min(TW, WW - C0);             // ragged last col-tile (96)
        const int S    = min(full, TWa - c0);
        if (S > 0) {
            h4 v[19];
#pragma unroll
            for (int k = 0; k < 19; ++k)
                v[k] = cs4[r][(c0 + k) ^ r];       // max idx (120)^7 <= 127
            __builtin_amdgcn_sched_barrier(0);     // keep 19 ds_reads batched

            h4 win = v[1] + v[2];
            win += v[3]; win += v[4]; win += v[5];
            win += v[6]; win += v[7]; win += v[8];
            win += v[9]; win += v[10];

            // slide 1: output cols c0+0 .. c0+7
#pragma unroll
            for (int p = 0; p < 8; ++p) {
                if (p >= S) break;
                win += v[p + 11];
                const float S1 = (float)win.x, S2 = (float)win.y;
                const float P  = (float)win.z, Q  = (float)win.w;
                const float m11 = S1 * S1, m22 = S2 * S2, m12 = S1 * S2;
                const float sigs = hu * (P + Q) - m11 - m22;
                const float s12  = qu * (P - Q) - m12;
                const float num  = (2.f * m12 + C1p) * (2.f * s12 + C2p);
                const float den  = (m11 + m22 + C1p) * (sigs + C2p);
                ssum += num * __builtin_amdgcn_rcpf(den);
                win -= v[p + 1];
            }
            // win now = slots c0+9 .. c0+18 (slide 2's prologue, carried free)

            // refill dead v[1..8] with slots c0+19 .. c0+26 (max 128^r <= 135)
#pragma unroll
            for (int k = 0; k < 8; ++k)
                v[k + 1] = cs4[r][(c0 + 19 + k) ^ r];
            __builtin_amdgcn_sched_barrier(0);

            // slide 2: output cols c0+8 .. c0+S-1 (max live slot c0+25 <= 127)
#pragma unroll
            for (int p = 0; p < 7; ++p) {
                if (p + 8 >= S) break;
                win += v[p + 1];                  // slot c0+19+p
                const float S1 = (float)win.x, S2 = (float)win.y;
                const float P  = (float)win.z, Q  = (float)win.w;
                const float m11 = S1 * S1, m22 = S2 * S2, m12 = S1 * S2;
                const float sigs = hu * (P + Q) - m11 - m22;
                const float s12  = qu * (P - Q) - m12;
                const float num  = (2.f * m12 + C1p) * (2.f * s12 + C2p);
                const float den  = (m11 + m22 + C1p) * (sigs + C2p);
                ssum += num * __builtin_amdgcn_rcpf(den);
                win -= v[p + 9];                  // slot c0+9+p
            }
        }
    }
    __builtin_amdgcn_s_setprio(0);

    // ---- Wave reduction -> atomicAdd into spread slots ----
    float v = ssum;
#pragma unroll
    for (int off = 32; off > 0; off >>= 1) v += __shfl_down(v, off, 64);
    if (cg == 0) {
        const int bid  = tx + 9 * (by + 128 * b);
        atomicAdd(ws + (bid & (NSLOT - 1)), v);
    }
}

__global__ void ssim_fin(const float* __restrict__ ws, float* __restrict__ out, int ntot) {
    const int lane = threadIdx.x;        // 64 threads
    float v = 0.f;
#pragma unroll
    for (int k = 0; k < NSLOT / 64; ++k) v += ws[lane + 64 * k];
#pragma unroll
    for (int off = 32; off > 0; off >>= 1) v += __shfl_down(v, off, 64);
    if (lane == 0) out[0] = 1.f - v / (float)ntot;
}

extern "C" void kernel_launch(void* const* d_in, const int* in_sizes, int n_in,
                              void* d_out, int out_size, void* d_ws, size_t ws_size,
                              hipStream_t stream) {
    const float* img1 = (const float*)d_in[0];
    const float* img2 = (const float*)d_in[1];
    const float* win  = (const float*)d_in[2];
    float* out = (float*)d_out;
    float* ws  = (float*)d_ws;
    const int ntot = in_sizes[0];                       // 32*1024*1024
    const int batches = ntot / (HH * WW);               // 32

    ssim_ws_init<<<dim3(1), dim3(NSLOT), 0, stream>>>(ws);
    dim3 grid((WW + TW - 1) / TW, HH / 8, batches);     // 9 x 128 x 32, 1 wave each
    ssim_main<<<grid, dim3(64), 0, stream>>>(img1, img2, win, ws);
    ssim_fin<<<dim3(1), dim3(64), 0, stream>>>(ws, out, ntot);
}

// Round 22
// 97.736 us; speedup vs baseline: 1.1064x; 1.1064x over previous
//
#include <hip/hip_runtime.h>

#define HH 1024
#define WW 1024
#define TW 116         // output cols per tile (even -> float2-aligned halo)
#define WLP 144        // colsum slots per row (max touched 141, no clamps)
#define NSLOT 1024     // partial-sum slots (atomic contention spread)
#define SSIM_C1 1e-4f
#define SSIM_C2 9e-4f

typedef float vf2 __attribute__((ext_vector_type(2)));
typedef __fp16 h2 __attribute__((ext_vector_type(2)));
typedef __fp16 h4 __attribute__((ext_vector_type(4)));

__global__ void ssim_ws_init(float* ws) { ws[threadIdx.x] = 0.f; }

// SSIM core for one output column, raw-sum space (u = 1/w):
#define SSIM_EMIT do { \
    const float S1 = (float)win.x, S2 = (float)win.y; \
    const float P  = (float)win.z, Q  = (float)win.w; \
    const float m11 = S1 * S1, m22 = S2 * S2, m12 = S1 * S2; \
    const float sigs = hu * (P + Q) - m11 - m22; \
    const float s12  = qu * (P - Q) - m12; \
    const float num  = (2.f * m12 + C1p) * (2.f * s12 + C2p); \
    const float den  = (m11 + m22 + C1p) * (sigs + C2p); \
    ssum += num * __builtin_amdgcn_rcpf(den); \
} while (0)

// Phase 2 over this wave's slab (two 8-col slides, win carried, v[19] profile)
#define PHASE2 do { if (S > 0) { \
    h4 v[19]; \
    _Pragma("unroll") \
    for (int k = 0; k < 19; ++k) v[k] = cs4[q][r][(c0 + k) ^ r]; \
    __builtin_amdgcn_sched_barrier(0); \
    h4 win = v[1] + v[2]; \
    win += v[3]; win += v[4]; win += v[5]; win += v[6]; \
    win += v[7]; win += v[8]; win += v[9]; win += v[10]; \
    _Pragma("unroll") \
    for (int p = 0; p < 8; ++p) { \
        if (p >= S) break; \
        win += v[p + 11]; SSIM_EMIT; win -= v[p + 1]; \
    } \
    _Pragma("unroll") \
    for (int k = 0; k < 8; ++k) v[k + 1] = cs4[q][r][(c0 + 19 + k) ^ r]; \
    __builtin_amdgcn_sched_barrier(0); \
    _Pragma("unroll") \
    for (int p = 0; p < 8; ++p) { \
        if (p + 8 >= S) break; \
        win += v[p + 1]; SSIM_EMIT; win -= v[p + 9]; \
    } \
} } while (0)

// Wave-autonomous + task-pipelined: each wave runs 4 sequential 8-row tasks;
// task t's 36 loads are issued BEFORE task (t-1)'s phase 2, so HBM latency
// hides under phase-2 VALU (T14 at task granularity). Single slab per wave is
// race-free (program order). (256,3): X/Y held across phase 2 -> ~130 VGPR
// peak; a 128 cap would spill (R10/R15/R18 lesson).
__global__ __launch_bounds__(256, 3) void ssim_main(const float* __restrict__ img1,
                                                    const float* __restrict__ img2,
                                                    const float* __restrict__ window,
                                                    float* __restrict__ ws)
{
    __shared__ h4 cs4[4][8][WLP];    // 36.9 KB; one 8-row slab per wave

    const int tx  = blockIdx.x;      // col tile: 0..8
    const int tyB = blockIdx.y;      // 128-row band: 0..7
    const int b   = blockIdx.z;      // batch
    const int t   = threadIdx.x;
    const int q   = t >> 6;          // wave 0..3
    const int cg  = t & 63;          // column pair
    const int C0  = tx * TW;
    const size_t ibase = (size_t)b * (size_t)(HH * WW);
    const float w = window[0];

    // column-side constants (same for all 4 tasks)
    const int gc   = C0 - 6 + 2 * cg;    // even -> 8B-aligned float2
    const bool cin = (tx >= 1) && (tx <= 7);
    const bool cok = (unsigned)gc < (unsigned)WW;
    const int gcc  = min(max(gc, 0), WW - 2);

    // phase-2 constants
    const float u   = __builtin_amdgcn_rcpf(w);   // = 121
    const float hu  = 0.5f  * u;
    const float qu  = 0.25f * u;
    const float C1p = SSIM_C1 * u * u;
    const float C2p = SSIM_C2 * u * u;
    const int r   = cg & 7;
    const int seg = cg >> 3;             // 8 segments x 16 cols
    const int c0  = seg * 16;            // 0..112
    const int TWa = min(TW, WW - C0);    // ragged last col-tile (96)
    const int S   = min(16, TWa - c0);

    float ssum = 0.f;
    vf2 X[18], Y[18];

#pragma unroll 1
    for (int tt = 0; tt < 4; ++tt) {
        const int R0 = tyB * 128 + tt * 32 + q * 8;
        const int jb = __builtin_amdgcn_readfirstlane(R0 - 5);

        // ---- issue task tt's 36 loads ----
        const bool rin = (R0 >= 8) && (R0 <= HH - 16);   // jb>=0 && jb+17<HH
        if (rin && cin) {
            const vf2* p1 = (const vf2*)(img1 + ibase + gc);
            const vf2* p2 = (const vf2*)(img2 + ibase + gc);
#pragma unroll
            for (int k = 0; k < 18; ++k) {
                const size_t off = (size_t)(jb + k) * (WW / 2);
                X[k] = p1[off];
                Y[k] = p2[off];
            }
        } else {
            const vf2* p1 = (const vf2*)(img1 + ibase + gcc);
            const vf2* p2 = (const vf2*)(img2 + ibase + gcc);
#pragma unroll
            for (int k = 0; k < 18; ++k) {
                const int j  = jb + k;
                const int jc = min(max(j, 0), HH - 1);
                const size_t off = (size_t)jc * (WW / 2);
                vf2 x = p1[off], y = p2[off];
                const bool ok = cok && ((unsigned)j < (unsigned)HH);
                if (!ok) { x = (vf2){0.f, 0.f}; y = (vf2){0.f, 0.f}; }
                X[k] = x; Y[k] = y;
            }
        }
        __builtin_amdgcn_sched_barrier(0);   // pin: loads issued above, work below

        // ---- phase 2 of PREVIOUS task while loads fly ----
        if (tt > 0) {
            PHASE2;
        }

        // ---- phase 1 of task tt (first X use -> vmcnt wait here) ----
        vf2 s1 = {0.f, 0.f}, s2 = {0.f, 0.f}, sp = {0.f, 0.f}, sq = {0.f, 0.f};
#pragma unroll
        for (int k = 0; k < 11; ++k) {
            const vf2 x = X[k], y = Y[k];
            const vf2 aa = x + y, dd = x - y;
            s1 += x; s2 += y;
            sp += aa * aa;
            sq += dd * dd;
        }
#pragma unroll
        for (int i = 0; i < 8; ++i) {
            if (i > 0) {
                const vf2 xn = X[10 + i], yn = Y[10 + i];   // static idx
                const vf2 xo = X[i - 1],  yo = Y[i - 1];
                const vf2 an = xn + yn, dn = xn - yn;
                const vf2 ao = xo + yo, dq = xo - yo;
                s1 += xn - xo;
                s2 += yn - yo;
                sp += (an - ao) * (an + ao);
                sq += (dn - dq) * (dn + dq);
            }
            const h2 loa = __builtin_amdgcn_cvt_pkrtz(s1.x, s2.x);
            const h2 hia = __builtin_amdgcn_cvt_pkrtz(sp.x, sq.x);
            const h2 lob = __builtin_amdgcn_cvt_pkrtz(s1.y, s2.y);
            const h2 hib = __builtin_amdgcn_cvt_pkrtz(sp.y, sq.y);
            cs4[q][i][(2 * cg)     ^ i] = __builtin_shufflevector(loa, hia, 0, 1, 2, 3);
            cs4[q][i][(2 * cg + 1) ^ i] = __builtin_shufflevector(lob, hib, 0, 1, 2, 3);
        }
    }

    // ---- phase 2 of the final task ----
    PHASE2;

    // ---- wave reduction -> atomicAdd into spread slots ----
    float v = ssum;
#pragma unroll
    for (int off = 32; off > 0; off >>= 1) v += __shfl_down(v, off, 64);
    if (cg == 0) {
        const int bid = tx + 9 * (tyB + 8 * b);
        atomicAdd(ws + ((bid * 4 + q) & (NSLOT - 1)), v);
    }
}

__global__ void ssim_fin(const float* __restrict__ ws, float* __restrict__ out, int ntot) {
    const int lane = threadIdx.x;        // 64 threads
    float v = 0.f;
#pragma unroll
    for (int k = 0; k < NSLOT / 64; ++k) v += ws[lane + 64 * k];
#pragma unroll
    for (int off = 32; off > 0; off >>= 1) v += __shfl_down(v, off, 64);
    if (lane == 0) out[0] = 1.f - v / (float)ntot;
}

extern "C" void kernel_launch(void* const* d_in, const int* in_sizes, int n_in,
                              void* d_out, int out_size, void* d_ws, size_t ws_size,
                              hipStream_t stream) {
    const float* img1 = (const float*)d_in[0];
    const float* img2 = (const float*)d_in[1];
    const float* win  = (const float*)d_in[2];
    float* out = (float*)d_out;
    float* ws  = (float*)d_ws;
    const int ntot = in_sizes[0];                       // 32*1024*1024
    const int batches = ntot / (HH * WW);               // 32

    ssim_ws_init<<<dim3(1), dim3(NSLOT), 0, stream>>>(ws);
    dim3 grid((WW + TW - 1) / TW, HH / 128, batches);   // 9 x 8 x 32
    ssim_main<<<grid, dim3(256), 0, stream>>>(img1, img2, win, ws);
    ssim_fin<<<dim3(1), dim3(64), 0, stream>>>(ws, out, ntot);
}